// Round 15
// baseline (180.643 us; speedup 1.0000x reference)
//
#include <hip/hip_runtime.h>

#define T_DIM 512
#define I_DIM 16
#define B_DIM 4096

typedef _Float16 f16x8 __attribute__((ext_vector_type(8)));
typedef float f32x4 __attribute__((ext_vector_type(4)));
typedef __fp16 hf2v __attribute__((ext_vector_type(2)));

union Frag { f16x8 v; __fp16 e[8]; uint4 u; };

__device__ __forceinline__ float fast_tanh(float x) {
    float e = __builtin_amdgcn_exp2f(x * 2.885390081777927f);
    return 1.0f - 2.0f * __builtin_amdgcn_rcpf(e + 1.0f);
}

// pack 8 f32 into B-frag element order {tile0 r0..r3, tile1 r0..r3}
__device__ __forceinline__ f16x8 pack8(float a0, float a1, float a2, float a3,
                                       float b0, float b1, float b2, float b3) {
    Frag f;
    hf2v p0 = __builtin_amdgcn_cvt_pkrtz(a0, a1);
    hf2v p1 = __builtin_amdgcn_cvt_pkrtz(a2, a3);
    hf2v p2 = __builtin_amdgcn_cvt_pkrtz(b0, b1);
    hf2v p3 = __builtin_amdgcn_cvt_pkrtz(b2, b3);
    f.e[0] = p0[0]; f.e[1] = p0[1]; f.e[2] = p1[0]; f.e[3] = p1[1];
    f.e[4] = p2[0]; f.e[5] = p2[1]; f.e[6] = p3[0]; f.e[7] = p3[1];
    return f.v;
}

// A-frag of W (32 cols) with q-permuted columns: j0..3 = W[r][4g..4g+3],
// j4..7 = W[r][16+4g..16+4g+3]   (q(8g+j) = 4g+j | 16+4g+j-4)
__device__ __forceinline__ f16x8 loadWq32(const float* W, int row, int g) {
    float4 a = *reinterpret_cast<const float4*>(W + row * 32 + 4 * g);
    float4 b = *reinterpret_cast<const float4*>(W + row * 32 + 16 + 4 * g);
    return pack8(a.x, a.y, a.z, a.w, b.x, b.y, b.z, b.w);
}
// Wih0 (16 cols): cols q(k)>=16 are zero-padded
__device__ __forceinline__ f16x8 loadWq16(const float* W, int row, int g) {
    float4 a = *reinterpret_cast<const float4*>(W + row * 16 + 4 * g);
    return pack8(a.x, a.y, a.z, a.w, 0.f, 0.f, 0.f, 0.f);
}

// One wave per 8 batch cols (dup'd to 16-wide tile). The q-relabel makes each
// step's tanh'd D registers directly the next MFMA's B-fragment:
// NO LDS, NO barriers, NO shuffles in the main loop.
__global__ void __launch_bounds__(64)
rnn2_mfma_noshuf(const float* __restrict__ x,
                 const float* __restrict__ Wih0, const float* __restrict__ Whh0,
                 const float* __restrict__ bih0, const float* __restrict__ bhh0,
                 const float* __restrict__ Wih1, const float* __restrict__ Whh1,
                 const float* __restrict__ bih1, const float* __restrict__ bhh1,
                 const float* __restrict__ fcw, const float* __restrict__ fcb,
                 float* __restrict__ out)
{
    const int l = threadIdx.x;
    const int c = l & 15;
    const int g = l >> 4;
    const int rowbase = blockIdx.x * 8;
    const size_t xcol = rowbase + (c & 7);

    // ---- weights (q-permuted cols) + biases-as-C ----
    f16x8 whh0A[2], wih1A[2], whh1A[2], wih0A[2];
    f32x4 b0C[2], b1C[2];
#pragma unroll
    for (int tt = 0; tt < 2; ++tt) {
        const int row = c + 16 * tt;
        whh0A[tt] = loadWq32(Whh0, row, g);
        wih1A[tt] = loadWq32(Wih1, row, g);
        whh1A[tt] = loadWq32(Whh1, row, g);
        wih0A[tt] = loadWq16(Wih0, row, g);
        const int r0 = 4 * g + 16 * tt;
        float4 bi0 = *reinterpret_cast<const float4*>(bih0 + r0);
        float4 bh0 = *reinterpret_cast<const float4*>(bhh0 + r0);
        b0C[tt][0] = bi0.x + bh0.x; b0C[tt][1] = bi0.y + bh0.y;
        b0C[tt][2] = bi0.z + bh0.z; b0C[tt][3] = bi0.w + bh0.w;
        float4 bi1 = *reinterpret_cast<const float4*>(bih1 + r0);
        float4 bh1 = *reinterpret_cast<const float4*>(bhh1 + r0);
        b1C[tt][0] = bi1.x + bh1.x; b1C[tt][1] = bi1.y + bh1.y;
        b1C[tt][2] = bi1.z + bh1.z; b1C[tt][3] = bi1.w + bh1.w;
    }

    const float* xlane = x + xcol * (size_t)(T_DIM * I_DIM) + 4 * g;

    Frag h1f;
    f32x4 Xacc[2], L1pre[2];
    float h20, h21, h22, h23, h24, h25, h26, h27;   // last h2 (f32, for FC)

    // ---- prologue: h1(0) = tanh(Wih0 x(0) + b0); Xacc = Wih0 x(1) + b0 ----
    {
        float4 x0 = *reinterpret_cast<const float4*>(xlane + 0 * I_DIM);
        Frag xf; xf.v = pack8(x0.x, x0.y, x0.z, x0.w, 0.f, 0.f, 0.f, 0.f);
        f32x4 Da = __builtin_amdgcn_mfma_f32_16x16x32_f16(wih0A[0], xf.v, b0C[0], 0, 0, 0);
        f32x4 Db = __builtin_amdgcn_mfma_f32_16x16x32_f16(wih0A[1], xf.v, b0C[1], 0, 0, 0);
        h1f.v = pack8(fast_tanh(Da[0]), fast_tanh(Da[1]), fast_tanh(Da[2]), fast_tanh(Da[3]),
                      fast_tanh(Db[0]), fast_tanh(Db[1]), fast_tanh(Db[2]), fast_tanh(Db[3]));
        float4 x1 = *reinterpret_cast<const float4*>(xlane + 1 * I_DIM);
        Frag xf1; xf1.v = pack8(x1.x, x1.y, x1.z, x1.w, 0.f, 0.f, 0.f, 0.f);
        Xacc[0] = __builtin_amdgcn_mfma_f32_16x16x32_f16(wih0A[0], xf1.v, b0C[0], 0, 0, 0);
        Xacc[1] = __builtin_amdgcn_mfma_f32_16x16x32_f16(wih0A[1], xf1.v, b0C[1], 0, 0, 0);
        L1pre[0] = b1C[0];
        L1pre[1] = b1C[1];
    }
    // x prefetch ring (2 slots, each 2 iterations deep)
    float4 xpA = *reinterpret_cast<const float4*>(xlane + 2 * I_DIM);
    float4 xpB = *reinterpret_cast<const float4*>(xlane + 3 * I_DIM);

    // body: iter t consumes x(t+2) from slot P, reloads x(t+4)
#define STEP(t, P)                                                                          \
    {                                                                                       \
        f32x4 D0a = __builtin_amdgcn_mfma_f32_16x16x32_f16(whh0A[0], h1f.v, Xacc[0], 0,0,0);\
        f32x4 D0b = __builtin_amdgcn_mfma_f32_16x16x32_f16(whh0A[1], h1f.v, Xacc[1], 0,0,0);\
        f32x4 D1a = __builtin_amdgcn_mfma_f32_16x16x32_f16(wih1A[0], h1f.v, L1pre[0],0,0,0);\
        f32x4 D1b = __builtin_amdgcn_mfma_f32_16x16x32_f16(wih1A[1], h1f.v, L1pre[1],0,0,0);\
        Frag xf; xf.v = pack8((P).x, (P).y, (P).z, (P).w, 0.f, 0.f, 0.f, 0.f);              \
        const int tn = ((t) + 4 < T_DIM) ? (t) + 4 : (T_DIM - 1);                           \
        (P) = *reinterpret_cast<const float4*>(xlane + (size_t)tn * I_DIM);                 \
        h1f.v = pack8(fast_tanh(D0a[0]), fast_tanh(D0a[1]),                                 \
                      fast_tanh(D0a[2]), fast_tanh(D0a[3]),                                 \
                      fast_tanh(D0b[0]), fast_tanh(D0b[1]),                                 \
                      fast_tanh(D0b[2]), fast_tanh(D0b[3]));                                \
        h20 = fast_tanh(D1a[0]); h21 = fast_tanh(D1a[1]);                                   \
        h22 = fast_tanh(D1a[2]); h23 = fast_tanh(D1a[3]);                                   \
        h24 = fast_tanh(D1b[0]); h25 = fast_tanh(D1b[1]);                                   \
        h26 = fast_tanh(D1b[2]); h27 = fast_tanh(D1b[3]);                                   \
        Frag h2f; h2f.v = pack8(h20, h21, h22, h23, h24, h25, h26, h27);                    \
        Xacc[0]  = __builtin_amdgcn_mfma_f32_16x16x32_f16(wih0A[0], xf.v,  b0C[0], 0,0,0);  \
        Xacc[1]  = __builtin_amdgcn_mfma_f32_16x16x32_f16(wih0A[1], xf.v,  b0C[1], 0,0,0);  \
        L1pre[0] = __builtin_amdgcn_mfma_f32_16x16x32_f16(whh1A[0], h2f.v, b1C[0], 0,0,0);  \
        L1pre[1] = __builtin_amdgcn_mfma_f32_16x16x32_f16(whh1A[1], h2f.v, b1C[1], 0,0,0);  \
    }

#pragma unroll 1
    for (int tb = 0; tb < T_DIM; tb += 2) {
        STEP(tb,     xpA)
        STEP(tb + 1, xpB)
    }
#undef STEP

    // ---- FC epilogue from h2(T-1) D-registers ----
    float4 fw0 = *reinterpret_cast<const float4*>(fcw + 4 * g);
    float4 fw1 = *reinterpret_cast<const float4*>(fcw + 16 + 4 * g);
    float part = fw0.x * h20 + fw0.y * h21 + fw0.z * h22 + fw0.w * h23
               + fw1.x * h24 + fw1.y * h25 + fw1.z * h26 + fw1.w * h27;
    part += __shfl_xor(part, 16, 64);
    part += __shfl_xor(part, 32, 64);
    if (l < 8) out[rowbase + l] = part + fcb[0];
}

extern "C" void kernel_launch(void* const* d_in, const int* in_sizes, int n_in,
                              void* d_out, int out_size, void* d_ws, size_t ws_size,
                              hipStream_t stream) {
    const float* x    = (const float*)d_in[0];
    const float* Wih0 = (const float*)d_in[1];
    const float* Whh0 = (const float*)d_in[2];
    const float* bih0 = (const float*)d_in[3];
    const float* bhh0 = (const float*)d_in[4];
    const float* Wih1 = (const float*)d_in[5];
    const float* Whh1 = (const float*)d_in[6];
    const float* bih1 = (const float*)d_in[7];
    const float* bhh1 = (const float*)d_in[8];
    const float* fcw  = (const float*)d_in[9];
    const float* fcb  = (const float*)d_in[10];
    float* out = (float*)d_out;

    dim3 grid(B_DIM / 8);   // 512 single-wave blocks, 8 batch cols each
    rnn2_mfma_noshuf<<<grid, 64, 0, stream>>>(x, Wih0, Whh0, bih0, bhh0,
                                              Wih1, Whh1, bih1, bhh1,
                                              fcw, fcb, out);
}

// Round 16
// 105.998 us; speedup vs baseline: 1.7042x; 1.7042x over previous
//
#include <hip/hip_runtime.h>

#define T_DIM 512
#define I_DIM 16
#define B_DIM 4096
#define K_CH 32            // steps per chunk

typedef _Float16 f16x8 __attribute__((ext_vector_type(8)));
typedef float f32x4 __attribute__((ext_vector_type(4)));
typedef __fp16 hf2v __attribute__((ext_vector_type(2)));

union Frag { f16x8 v; __fp16 e[8]; uint4 u; };

__device__ __forceinline__ float fast_tanh(float x) {
    float e = __builtin_amdgcn_exp2f(x * 2.885390081777927f);
    return 1.0f - 2.0f * __builtin_amdgcn_rcpf(e + 1.0f);
}

__device__ __forceinline__ f16x8 pack8(float a0, float a1, float a2, float a3,
                                       float b0, float b1, float b2, float b3) {
    Frag f;
    hf2v p0 = __builtin_amdgcn_cvt_pkrtz(a0, a1);
    hf2v p1 = __builtin_amdgcn_cvt_pkrtz(a2, a3);
    hf2v p2 = __builtin_amdgcn_cvt_pkrtz(b0, b1);
    hf2v p3 = __builtin_amdgcn_cvt_pkrtz(b2, b3);
    f.e[0] = p0[0]; f.e[1] = p0[1]; f.e[2] = p1[0]; f.e[3] = p1[1];
    f.e[4] = p2[0]; f.e[5] = p2[1]; f.e[6] = p3[0]; f.e[7] = p3[1];
    return f.v;
}
__device__ __forceinline__ f16x8 tanhpack(f32x4 a, f32x4 b) {
    return pack8(fast_tanh(a[0]), fast_tanh(a[1]), fast_tanh(a[2]), fast_tanh(a[3]),
                 fast_tanh(b[0]), fast_tanh(b[1]), fast_tanh(b[2]), fast_tanh(b[3]));
}
// q-permuted A-frag loads (q(8g+j) = 4g+j | 16+4g+j-4), as verified in r15
__device__ __forceinline__ f16x8 loadWq32(const float* W, int row, int g) {
    float4 a = *reinterpret_cast<const float4*>(W + row * 32 + 4 * g);
    float4 b = *reinterpret_cast<const float4*>(W + row * 32 + 16 + 4 * g);
    return pack8(a.x, a.y, a.z, a.w, b.x, b.y, b.z, b.w);
}
__device__ __forceinline__ f16x8 loadWq16(const float* W, int row, int g) {
    float4 a = *reinterpret_cast<const float4*>(W + row * 16 + 4 * g);
    return pack8(a.x, a.y, a.z, a.w, 0.f, 0.f, 0.f, 0.f);
}

// Producer-consumer wave specialization:
//   wave0: layer-1 recurrence (no-shuffle, in-register), streams h1(t) frags
//          into a 2-chunk LDS ring (K_CH steps per chunk, 1KB/step).
//   wave1: trails one chunk; ds_read_b128 gives its B-frag directly
//          (producer lane == consumer lane); layer-2 recurrence + FC.
// __syncthreads only at chunk boundaries (17 total for T=512).
__global__ void __launch_bounds__(128)
rnn2_pc_kernel(const float* __restrict__ x,
               const float* __restrict__ Wih0, const float* __restrict__ Whh0,
               const float* __restrict__ bih0, const float* __restrict__ bhh0,
               const float* __restrict__ Wih1, const float* __restrict__ Whh1,
               const float* __restrict__ bih1, const float* __restrict__ bhh1,
               const float* __restrict__ fcw, const float* __restrict__ fcb,
               float* __restrict__ out)
{
    const int tid = threadIdx.x;
    const int l   = tid & 63;
    const int wid = tid >> 6;
    const int c   = l & 15;
    const int g   = l >> 4;
    const int rowbase = blockIdx.x * 8;

    __shared__ __fp16 ring[2][K_CH][64][8];   // 64 KB

    // wT0/wT1/bC: wave0 -> {Whh0, Wih0, b0}; wave1 -> {Wih1, Whh1, b1}
    f16x8 wT0[2], wT1[2];
    f32x4 bC[2];
    Frag  h1f;
    f32x4 Xacc[2], L1pre[2];
    float4 xpA, xpB;
    const float* xlane = nullptr;
    float h20=0.f,h21=0.f,h22=0.f,h23=0.f,h24=0.f,h25=0.f,h26=0.f,h27=0.f;

    if (wid == 0) {
#pragma unroll
        for (int tt = 0; tt < 2; ++tt) {
            const int row = c + 16 * tt;
            wT0[tt] = loadWq32(Whh0, row, g);
            wT1[tt] = loadWq16(Wih0, row, g);
            const int r0 = 4 * g + 16 * tt;
            float4 bi = *reinterpret_cast<const float4*>(bih0 + r0);
            float4 bh = *reinterpret_cast<const float4*>(bhh0 + r0);
            bC[tt][0] = bi.x + bh.x; bC[tt][1] = bi.y + bh.y;
            bC[tt][2] = bi.z + bh.z; bC[tt][3] = bi.w + bh.w;
        }
        const size_t xcol = rowbase + (c & 7);
        xlane = x + xcol * (size_t)(T_DIM * I_DIM) + 4 * g;
    } else {
#pragma unroll
        for (int tt = 0; tt < 2; ++tt) {
            const int row = c + 16 * tt;
            wT0[tt] = loadWq32(Wih1, row, g);
            wT1[tt] = loadWq32(Whh1, row, g);
            const int r0 = 4 * g + 16 * tt;
            float4 bi = *reinterpret_cast<const float4*>(bih1 + r0);
            float4 bh = *reinterpret_cast<const float4*>(bhh1 + r0);
            bC[tt][0] = bi.x + bh.x; bC[tt][1] = bi.y + bh.y;
            bC[tt][2] = bi.z + bh.z; bC[tt][3] = bi.w + bh.w;
        }
        L1pre[0] = bC[0];      // h2(-1) = 0
        L1pre[1] = bC[1];
    }

#define PSTEP(t, P)                                                                         \
    {                                                                                       \
        f32x4 D0a = __builtin_amdgcn_mfma_f32_16x16x32_f16(wT0[0], h1f.v, Xacc[0], 0,0,0);  \
        f32x4 D0b = __builtin_amdgcn_mfma_f32_16x16x32_f16(wT0[1], h1f.v, Xacc[1], 0,0,0);  \
        Frag xf; xf.v = pack8((P).x, (P).y, (P).z, (P).w, 0.f, 0.f, 0.f, 0.f);              \
        const int tn = ((t) + 3 < T_DIM) ? (t) + 3 : (T_DIM - 1);                           \
        (P) = *reinterpret_cast<const float4*>(xlane + (size_t)tn * I_DIM);                 \
        h1f.v = tanhpack(D0a, D0b);                                                         \
        *reinterpret_cast<uint4*>(&ring[((t) >> 5) & 1][(t) & 31][l][0]) = h1f.u;           \
        Xacc[0] = __builtin_amdgcn_mfma_f32_16x16x32_f16(wT1[0], xf.v, bC[0], 0,0,0);       \
        Xacc[1] = __builtin_amdgcn_mfma_f32_16x16x32_f16(wT1[1], xf.v, bC[1], 0,0,0);       \
    }

#define CSTEP(t)                                                                            \
    {                                                                                       \
        Frag h1B; h1B.u = *reinterpret_cast<const uint4*>(&ring[((t) >> 5) & 1][(t) & 31][l][0]); \
        f32x4 D1a = __builtin_amdgcn_mfma_f32_16x16x32_f16(wT0[0], h1B.v, L1pre[0], 0,0,0); \
        f32x4 D1b = __builtin_amdgcn_mfma_f32_16x16x32_f16(wT0[1], h1B.v, L1pre[1], 0,0,0); \
        h20 = fast_tanh(D1a[0]); h21 = fast_tanh(D1a[1]);                                   \
        h22 = fast_tanh(D1a[2]); h23 = fast_tanh(D1a[3]);                                   \
        h24 = fast_tanh(D1b[0]); h25 = fast_tanh(D1b[1]);                                   \
        h26 = fast_tanh(D1b[2]); h27 = fast_tanh(D1b[3]);                                   \
        Frag h2f; h2f.v = pack8(h20, h21, h22, h23, h24, h25, h26, h27);                    \
        L1pre[0] = __builtin_amdgcn_mfma_f32_16x16x32_f16(wT1[0], h2f.v, bC[0], 0,0,0);     \
        L1pre[1] = __builtin_amdgcn_mfma_f32_16x16x32_f16(wT1[1], h2f.v, bC[1], 0,0,0);     \
    }

#pragma unroll 1
    for (int p = 0; p <= T_DIM / K_CH; ++p) {
        if (wid == 0 && p < T_DIM / K_CH) {
            if (p == 0) {
                // prologue: h1(0), h1(1); then t = 2..31
                float4 x0 = *reinterpret_cast<const float4*>(xlane + 0 * I_DIM);
                Frag xf0; xf0.v = pack8(x0.x, x0.y, x0.z, x0.w, 0.f, 0.f, 0.f, 0.f);
                f32x4 Da = __builtin_amdgcn_mfma_f32_16x16x32_f16(wT1[0], xf0.v, bC[0], 0,0,0);
                f32x4 Db = __builtin_amdgcn_mfma_f32_16x16x32_f16(wT1[1], xf0.v, bC[1], 0,0,0);
                h1f.v = tanhpack(Da, Db);
                *reinterpret_cast<uint4*>(&ring[0][0][l][0]) = h1f.u;      // h1(0)
                float4 x1 = *reinterpret_cast<const float4*>(xlane + 1 * I_DIM);
                Frag xf1; xf1.v = pack8(x1.x, x1.y, x1.z, x1.w, 0.f, 0.f, 0.f, 0.f);
                Xacc[0] = __builtin_amdgcn_mfma_f32_16x16x32_f16(wT1[0], xf1.v, bC[0], 0,0,0);
                Xacc[1] = __builtin_amdgcn_mfma_f32_16x16x32_f16(wT1[1], xf1.v, bC[1], 0,0,0);
                // t = 1
                f32x4 D0a = __builtin_amdgcn_mfma_f32_16x16x32_f16(wT0[0], h1f.v, Xacc[0], 0,0,0);
                f32x4 D0b = __builtin_amdgcn_mfma_f32_16x16x32_f16(wT0[1], h1f.v, Xacc[1], 0,0,0);
                float4 x2 = *reinterpret_cast<const float4*>(xlane + 2 * I_DIM);
                h1f.v = tanhpack(D0a, D0b);
                *reinterpret_cast<uint4*>(&ring[0][1][l][0]) = h1f.u;      // h1(1)
                Frag xf2; xf2.v = pack8(x2.x, x2.y, x2.z, x2.w, 0.f, 0.f, 0.f, 0.f);
                Xacc[0] = __builtin_amdgcn_mfma_f32_16x16x32_f16(wT1[0], xf2.v, bC[0], 0,0,0);
                Xacc[1] = __builtin_amdgcn_mfma_f32_16x16x32_f16(wT1[1], xf2.v, bC[1], 0,0,0);
                xpA = *reinterpret_cast<const float4*>(xlane + 3 * I_DIM);
                xpB = *reinterpret_cast<const float4*>(xlane + 4 * I_DIM);
#pragma unroll 2
                for (int s = 2; s < K_CH; s += 2) { PSTEP(s, xpA) PSTEP(s + 1, xpB) }
            } else {
                const int t0 = p * K_CH;
#pragma unroll 2
                for (int s = 0; s < K_CH; s += 2) { PSTEP(t0 + s, xpA) PSTEP(t0 + s + 1, xpB) }
            }
        }
        if (wid == 1 && p >= 1) {
            const int t0 = (p - 1) * K_CH;
#pragma unroll 2
            for (int s = 0; s < K_CH; s += 2) { CSTEP(t0 + s) CSTEP(t0 + s + 1) }
        }
        __syncthreads();
    }
#undef PSTEP
#undef CSTEP

    // ---- FC epilogue from wave1's h2(T-1) registers ----
    if (wid == 1) {
        float4 fw0 = *reinterpret_cast<const float4*>(fcw + 4 * g);
        float4 fw1 = *reinterpret_cast<const float4*>(fcw + 16 + 4 * g);
        float part = fw0.x * h20 + fw0.y * h21 + fw0.z * h22 + fw0.w * h23
                   + fw1.x * h24 + fw1.y * h25 + fw1.z * h26 + fw1.w * h27;
        part += __shfl_xor(part, 16, 64);
        part += __shfl_xor(part, 32, 64);
        if (l < 8) out[rowbase + l] = part + fcb[0];
    }
}

extern "C" void kernel_launch(void* const* d_in, const int* in_sizes, int n_in,
                              void* d_out, int out_size, void* d_ws, size_t ws_size,
                              hipStream_t stream) {
    const float* x    = (const float*)d_in[0];
    const float* Wih0 = (const float*)d_in[1];
    const float* Whh0 = (const float*)d_in[2];
    const float* bih0 = (const float*)d_in[3];
    const float* bhh0 = (const float*)d_in[4];
    const float* Wih1 = (const float*)d_in[5];
    const float* Whh1 = (const float*)d_in[6];
    const float* bih1 = (const float*)d_in[7];
    const float* bhh1 = (const float*)d_in[8];
    const float* fcw  = (const float*)d_in[9];
    const float* fcb  = (const float*)d_in[10];
    float* out = (float*)d_out;

    dim3 grid(B_DIM / 8);   // 512 blocks x 2 waves = 1024 waves = 4/CU
    rnn2_pc_kernel<<<grid, 128, 0, stream>>>(x, Wih0, Whh0, bih0, bhh0,
                                             Wih1, Whh1, bih1, bhh1,
                                             fcw, fcb, out);
}